// Round 1
// baseline (2478.743 us; speedup 1.0000x reference)
//
#include <hip/hip_runtime.h>

#define NPAT  16384
#define DF    1024
#define BATCH 512
#define CAP   64
#define MAXIT 8

#define BM 128
#define BN 128
#define BK 16
#define LDT 20   // padded LDS row stride (floats): conflict-free for this mapping

__device__ __forceinline__ unsigned encf(float f) {
  unsigned u = __float_as_uint(f);
  return (u & 0x80000000u) ? ~u : (u | 0x80000000u);
}
__device__ __forceinline__ float decf(unsigned e) {
  unsigned u = (e & 0x80000000u) ? (e & 0x7FFFFFFFu) : ~e;
  return __uint_as_float(u);
}

// QT[n][k] = Q[k][n]
__global__ void k_transpose(const float* __restrict__ Q, float* __restrict__ QT) {
  __shared__ float tile[32][33];
  int tx = threadIdx.x & 31;
  int ty = threadIdx.x >> 5;            // 0..7
  int n0 = blockIdx.x * 32;
  int k0 = blockIdx.y * 32;
#pragma unroll
  for (int s = 0; s < 4; ++s)
    tile[ty + 8 * s][tx] = Q[(size_t)(k0 + ty + 8 * s) * BATCH + n0 + tx];
  __syncthreads();
#pragma unroll
  for (int s = 0; s < 4; ++s)
    QT[(size_t)(n0 + ty + 8 * s) * DF + k0 + tx] = tile[tx][ty + 8 * s];
}

// C[M=NPAT][N=BATCH] = A[M][K] * Bt[N][K]^T   (fp32, vector ALU)
__global__ __launch_bounds__(256) void k_gemm(const float* __restrict__ A,
                                              const float* __restrict__ Bt,
                                              float* __restrict__ C) {
  __shared__ float As[BM][LDT];
  __shared__ float Bs[BN][LDT];
  const int t  = threadIdx.x;
  const int tx = t & 15;
  const int ty = t >> 4;
  const int row0 = blockIdx.y * BM;
  const int col0 = blockIdx.x * BN;

  float acc[8][8];
#pragma unroll
  for (int i = 0; i < 8; ++i)
#pragma unroll
    for (int j = 0; j < 8; ++j) acc[i][j] = 0.f;

  for (int k0 = 0; k0 < DF; k0 += BK) {
#pragma unroll
    for (int l = 0; l < 2; ++l) {
      int id = t + l * 256;          // 0..511 over [row 0..127][f4 0..3]
      int r = id >> 2, f = (id & 3) * 4;
      float4 va = *(const float4*)(A  + (size_t)(row0 + r) * DF + k0 + f);
      float4 vb = *(const float4*)(Bt + (size_t)(col0 + r) * DF + k0 + f);
      *(float4*)(&As[r][f]) = va;
      *(float4*)(&Bs[r][f]) = vb;
    }
    __syncthreads();
#pragma unroll
    for (int kk = 0; kk < BK; ++kk) {
      float a[8], b[8];
#pragma unroll
      for (int i = 0; i < 8; ++i) a[i] = As[ty + 16 * i][kk];
#pragma unroll
      for (int j = 0; j < 8; ++j) b[j] = Bs[tx + 16 * j][kk];
#pragma unroll
      for (int i = 0; i < 8; ++i)
#pragma unroll
        for (int j = 0; j < 8; ++j)
          acc[i][j] = fmaf(a[i], b[j], acc[i][j]);
    }
    __syncthreads();
  }
#pragma unroll
  for (int i = 0; i < 8; ++i) {
    size_t r = row0 + ty + 16 * i;
#pragma unroll
    for (int j = 0; j < 8; ++j)
      C[r * BATCH + col0 + tx + 16 * j] = acc[i][j];
  }
}

__global__ void k_init(unsigned* __restrict__ colMaxEnc, int* __restrict__ candCount) {
  int i = threadIdx.x;
  colMaxEnc[i] = 0u;   // below encf of any real float
  candCount[i] = 0;
}

// thread = column; block = 128-row chunk. Coalesced along columns.
__global__ void k_colmax(const float* __restrict__ Z, unsigned* __restrict__ colMaxEnc) {
  int col = threadIdx.x;
  int r0 = blockIdx.x * 128;
  float m = -3.4e38f;
  for (int r = 0; r < 128; ++r)
    m = fmaxf(m, Z[(size_t)(r0 + r) * BATCH + col]);
  atomicMax(&colMaxEnc[col], encf(m));
}

// sparsemax support is confined to z > max-1 (tau >= max-1 since p_max <= 1)
__global__ void k_collect(const float* __restrict__ Z, const unsigned* __restrict__ colMaxEnc,
                          int* __restrict__ candCount, int* __restrict__ candIdx,
                          float* __restrict__ candVal) {
  int col = threadIdx.x;
  int r0 = blockIdx.x * 128;
  float thr = decf(colMaxEnc[col]) - 1.0f;
  for (int r = 0; r < 128; ++r) {
    float z = Z[(size_t)(r0 + r) * BATCH + col];
    if (z > thr) {
      int p = atomicAdd(&candCount[col], 1);
      if (p < CAP) {
        candIdx[col * CAP + p] = r0 + r;
        candVal[col * CAP + p] = z;
      }
    }
  }
}

// exact sparsemax over the (tiny) candidate set: sort desc, threshold rule
__global__ void k_tau(const int* __restrict__ candCount, int* __restrict__ candIdx,
                      float* __restrict__ candVal, int* __restrict__ suppK,
                      float* __restrict__ tauArr) {
  int b = threadIdx.x;   // 512 threads, 1 block
  int m = candCount[b];
  if (m > CAP) m = CAP;
  float cv[CAP]; int ci[CAP];
  for (int j = 0; j < m; ++j) { cv[j] = candVal[b * CAP + j]; ci[j] = candIdx[b * CAP + j]; }
  for (int j = 1; j < m; ++j) {          // insertion sort descending
    float v = cv[j]; int id = ci[j];
    int l = j - 1;
    while (l >= 0 && cv[l] < v) { cv[l + 1] = cv[l]; ci[l + 1] = ci[l]; --l; }
    cv[l + 1] = v; ci[l + 1] = id;
  }
  float cum = 0.f; int k = 0; float tau = 0.f;
  for (int j = 0; j < m; ++j) {
    cum += cv[j];
    float tj = (cum - 1.0f) / (float)(j + 1);
    if (cv[j] > tj) { k = j + 1; tau = tj; }
  }
  suppK[b] = k;
  tauArr[b] = tau;
  for (int j = 0; j < m; ++j) { candVal[b * CAP + j] = cv[j]; candIdx[b * CAP + j] = ci[j]; }
}

// QT[b][:] = sum_j (cv_j - tau) * X[idx_j][:]   (p is support-sparse)
__global__ void k_qupdate(const float* __restrict__ X, const int* __restrict__ candIdx,
                          const float* __restrict__ candVal, const int* __restrict__ suppK,
                          const float* __restrict__ tauArr, float* __restrict__ QT) {
  int b = blockIdx.x;
  int t = threadIdx.x;
  int k = suppK[b];
  float tau = tauArr[b];
  float a0 = 0.f, a1 = 0.f, a2 = 0.f, a3 = 0.f;
  for (int j = 0; j < k; ++j) {
    float w = candVal[b * CAP + j] - tau;
    const float* xr = X + (size_t)candIdx[b * CAP + j] * DF;
    a0 += w * xr[t];
    a1 += w * xr[t + 256];
    a2 += w * xr[t + 512];
    a3 += w * xr[t + 768];
  }
  QT[(size_t)b * DF + t]       = a0;
  QT[(size_t)b * DF + t + 256] = a1;
  QT[(size_t)b * DF + t + 512] = a2;
  QT[(size_t)b * DF + t + 768] = a3;
}

// d_out pre-zeroed; write only the support entries of p
__global__ void k_scatter(const int* __restrict__ candIdx, const float* __restrict__ candVal,
                          const int* __restrict__ suppK, const float* __restrict__ tauArr,
                          float* __restrict__ out) {
  int b = blockIdx.x * blockDim.x + threadIdx.x;
  if (b >= BATCH) return;
  int k = suppK[b];
  float tau = tauArr[b];
  for (int j = 0; j < k; ++j)
    out[(size_t)candIdx[b * CAP + j] * BATCH + b] = candVal[b * CAP + j] - tau;
}

extern "C" void kernel_launch(void* const* d_in, const int* in_sizes, int n_in,
                              void* d_out, int out_size, void* d_ws, size_t ws_size,
                              hipStream_t stream) {
  const float* X = (const float*)d_in[0];   // [16384][1024]
  const float* Q = (const float*)d_in[1];   // [1024][512]
  float* out = (float*)d_out;               // [16384][512]

  char* ws = (char*)d_ws;
  float*    Z         = (float*)ws;                                    // 32 MB
  float*    QT        = (float*)(ws + (size_t)NPAT * BATCH * 4);       // 2 MB
  unsigned* colMaxEnc = (unsigned*)((char*)QT + (size_t)BATCH * DF * 4);
  int*      candCount = (int*)(colMaxEnc + BATCH);
  int*      candIdx   = candCount + BATCH;
  float*    candVal   = (float*)(candIdx + BATCH * CAP);
  int*      suppK     = (int*)(candVal + BATCH * CAP);
  float*    tauArr    = (float*)(suppK + BATCH);

  hipMemsetAsync(d_out, 0, (size_t)out_size * sizeof(float), stream);

  k_transpose<<<dim3(BATCH / 32, DF / 32), 256, 0, stream>>>(Q, QT);

  for (int it = 0; it < MAXIT; ++it) {
    k_init<<<1, BATCH, 0, stream>>>(colMaxEnc, candCount);
    k_gemm<<<dim3(BATCH / BN, NPAT / BM), 256, 0, stream>>>(X, QT, Z);
    k_colmax<<<NPAT / 128, BATCH, 0, stream>>>(Z, colMaxEnc);
    k_collect<<<NPAT / 128, BATCH, 0, stream>>>(Z, colMaxEnc, candCount, candIdx, candVal);
    k_tau<<<1, BATCH, 0, stream>>>(candCount, candIdx, candVal, suppK, tauArr);
    if (it < MAXIT - 1)
      k_qupdate<<<BATCH, 256, 0, stream>>>(X, candIdx, candVal, suppK, tauArr, QT);
  }
  k_scatter<<<2, 256, 0, stream>>>(candIdx, candVal, suppK, tauArr, out);
}

// Round 4
// 1007.123 us; speedup vs baseline: 2.4612x; 2.4612x over previous
//
#include <hip/hip_runtime.h>
#include <hip/hip_bf16.h>

#define NPAT  16384
#define DF    1024
#define BATCH 512
#define CAP   16
#define MAXIT 8

typedef __attribute__((ext_vector_type(8))) short short8v;  // 8 bf16 (4 VGPRs)
typedef __attribute__((ext_vector_type(4))) float f32x4;
typedef unsigned short ushortT;

__device__ __forceinline__ unsigned encf(float f) {
  unsigned u = __float_as_uint(f);
  return (u & 0x80000000u) ? ~u : (u | 0x80000000u);
}
__device__ __forceinline__ float decf(unsigned e) {
  unsigned u = (e & 0x80000000u) ? (e & 0x7FFFFFFFu) : ~e;
  return __uint_as_float(u);
}

// QT[n][k] = Q[k][n]
__global__ void k_transpose(const float* __restrict__ Q, float* __restrict__ QT) {
  __shared__ float tile[32][33];
  int tx = threadIdx.x & 31;
  int ty = threadIdx.x >> 5;
  int n0 = blockIdx.x * 32;
  int k0 = blockIdx.y * 32;
#pragma unroll
  for (int s = 0; s < 4; ++s)
    tile[ty + 8 * s][tx] = Q[(size_t)(k0 + ty + 8 * s) * BATCH + n0 + tx];
  __syncthreads();
#pragma unroll
  for (int s = 0; s < 4; ++s)
    QT[(size_t)(n0 + ty + 8 * s) * DF + k0 + tx] = tile[tx][ty + 8 * s];
}

// Split fp32 -> (hi bf16, lo bf16 residual). x = hi + lo + O(2^-16 |x|)
__device__ __forceinline__ void bsplit(float x, ushortT& h, ushortT& l) {
  __hip_bfloat16 hb = __float2bfloat16(x);
  float hf = __bfloat162float(hb);
  __hip_bfloat16 lb = __float2bfloat16(x - hf);
  h = *(ushortT*)&hb;
  l = *(ushortT*)&lb;
}

// X fp32 [NPAT][DF] -> Xh, Xl bf16. Runs every call (harness re-poisons ws).
__global__ void k_xsplit(const float4* __restrict__ X4, unsigned* __restrict__ Xh,
                         unsigned* __restrict__ Xl) {
  size_t i = (size_t)blockIdx.x * blockDim.x + threadIdx.x;  // 4 elems/thread
  float4 v = X4[i];
  ushortT h0, h1, h2, h3, l0, l1, l2, l3;
  bsplit(v.x, h0, l0); bsplit(v.y, h1, l1);
  bsplit(v.z, h2, l2); bsplit(v.w, h3, l3);
  Xh[2 * i]     = (unsigned)h0 | ((unsigned)h1 << 16);
  Xh[2 * i + 1] = (unsigned)h2 | ((unsigned)h3 << 16);
  Xl[2 * i]     = (unsigned)l0 | ((unsigned)l1 << 16);
  Xl[2 * i + 1] = (unsigned)l2 | ((unsigned)l3 << 16);
}

// QT fp32 [BATCH][DF] -> Qh, Ql bf16; block 0 also clears per-iter counters.
__global__ void k_qsplit(const float4* __restrict__ QT4, unsigned* __restrict__ Qh,
                         unsigned* __restrict__ Ql, unsigned* __restrict__ colMaxEnc,
                         int* __restrict__ candCount, const int* __restrict__ conv) {
  if (*conv) return;
  int t = threadIdx.x;
  if (blockIdx.x == 0) {
    colMaxEnc[t] = 0u; colMaxEnc[t + 256] = 0u;
    candCount[t] = 0;  candCount[t + 256] = 0;
  }
  size_t i = (size_t)blockIdx.x * blockDim.x + t;
  float4 v = QT4[i];
  ushortT h0, h1, h2, h3, l0, l1, l2, l3;
  bsplit(v.x, h0, l0); bsplit(v.y, h1, l1);
  bsplit(v.z, h2, l2); bsplit(v.w, h3, l3);
  Qh[2 * i]     = (unsigned)h0 | ((unsigned)h1 << 16);
  Qh[2 * i + 1] = (unsigned)h2 | ((unsigned)h3 << 16);
  Ql[2 * i]     = (unsigned)l0 | ((unsigned)l1 << 16);
  Ql[2 * i + 1] = (unsigned)l2 | ((unsigned)l3 << 16);
}

// Z[m][n] = sum over K'=3072 of Ahat[m][k']*Bhat[n][k'], where segments
// (0,1,2) pair (Xh,Qh),(Xh,Ql),(Xl,Qh). 128x128 tile, BK=64, 4 waves.
// LDS [128][64] bf16, XOR chunk swizzle c' = c ^ (r&7) applied at the
// pre-swizzled GLOBAL source; LDS writes linear (conflict-free), frag
// ds_read_b128 lands 2-way (free). Epilogue fuses per-column max.
__global__ __launch_bounds__(256) void k_gemm(
    const ushortT* __restrict__ Xh, const ushortT* __restrict__ Xl,
    const ushortT* __restrict__ Qh, const ushortT* __restrict__ Ql,
    float* __restrict__ Z, unsigned* __restrict__ colMaxEnc,
    const int* __restrict__ conv) {
  if (*conv) return;
  __shared__ ushortT As[128 * 64];
  __shared__ ushortT Bs[128 * 64];
  __shared__ unsigned cmax[128];
  const int t  = threadIdx.x;
  const int l  = t & 63;
  const int w  = t >> 6;
  const int wr = w >> 1, wc = w & 1;
  const int lr = l & 15;   // row/col within fragment
  const int lk = l >> 4;   // k-octet selector
  const int row0 = blockIdx.y * 128;
  const int col0 = blockIdx.x * 128;

  f32x4 acc[4][4];
#pragma unroll
  for (int i = 0; i < 4; ++i)
#pragma unroll
    for (int j = 0; j < 4; ++j) acc[i][j] = (f32x4)0.f;

  int rA[4], sA[4];
#pragma unroll
  for (int i = 0; i < 4; ++i) {
    int id = i * 256 + t;
    int r = id >> 3, c = id & 7;
    rA[i] = r;
    sA[i] = ((c ^ (r & 7)) << 3);   // pre-swizzled source k-offset (shorts)
  }

  uint4 ra[4], rb[4];
#pragma unroll
  for (int i = 0; i < 4; ++i) {     // prefetch step 0 (seg 0: Xh,Qh)
    ra[i] = *(const uint4*)(Xh + (size_t)(row0 + rA[i]) * DF + sA[i]);
    rb[i] = *(const uint4*)(Qh + (size_t)(col0 + rA[i]) * DF + sA[i]);
  }

  for (int step = 0; step < 48; ++step) {
    __syncthreads();
#pragma unroll
    for (int i = 0; i < 4; ++i) {   // linear LDS write: lane-consecutive 16B
      int id = i * 256 + t;
      *(uint4*)(&As[id * 8]) = ra[i];
      *(uint4*)(&Bs[id * 8]) = rb[i];
    }
    __syncthreads();
    if (step < 47) {                // prefetch next tile under this compute
      int k0 = (step + 1) * 64;
      int seg = k0 >> 10;
      int klocal = k0 & 1023;
      const ushortT* Ab = (seg == 2) ? Xl : Xh;
      const ushortT* Bb = (seg == 1) ? Ql : Qh;
#pragma unroll
      for (int i = 0; i < 4; ++i) {
        ra[i] = *(const uint4*)(Ab + (size_t)(row0 + rA[i]) * DF + klocal + sA[i]);
        rb[i] = *(const uint4*)(Bb + (size_t)(col0 + rA[i]) * DF + klocal + sA[i]);
      }
    }
#pragma unroll
    for (int kk = 0; kk < 2; ++kk) {
      short8v af[4], bf[4];
#pragma unroll
      for (int i = 0; i < 4; ++i) {
        int row = wr * 64 + i * 16 + lr;
        int ch = (kk * 4 + lk) ^ (row & 7);
        af[i] = *(const short8v*)(&As[row * 64 + ch * 8]);
      }
#pragma unroll
      for (int j = 0; j < 4; ++j) {
        int col = wc * 64 + j * 16 + lr;
        int ch = (kk * 4 + lk) ^ (col & 7);
        bf[j] = *(const short8v*)(&Bs[col * 64 + ch * 8]);
      }
#pragma unroll
      for (int i = 0; i < 4; ++i)
#pragma unroll
        for (int j = 0; j < 4; ++j)
          acc[i][j] = __builtin_amdgcn_mfma_f32_16x16x32_bf16(af[i], bf[j], acc[i][j], 0, 0, 0);
    }
  }

  // Epilogue: store Z (C layout: col = l&15, row = (l>>4)*4 + reg) + col max
  if (t < 128) cmax[t] = 0u;
  __syncthreads();
#pragma unroll
  for (int j = 0; j < 4; ++j) {
    int col = col0 + wc * 64 + j * 16 + lr;
    float cm = -3.4e38f;
#pragma unroll
    for (int i = 0; i < 4; ++i) {
      int rbase = row0 + wr * 64 + i * 16 + lk * 4;
#pragma unroll
      for (int q = 0; q < 4; ++q) {
        float v = acc[i][j][q];
        Z[(size_t)(rbase + q) * BATCH + col] = v;
        cm = fmaxf(cm, v);
      }
    }
    cm = fmaxf(cm, __shfl_xor(cm, 16));
    cm = fmaxf(cm, __shfl_xor(cm, 32));
    if (lk == 0) atomicMax(&cmax[wc * 64 + j * 16 + lr], encf(cm));
  }
  __syncthreads();
  if (t < 128) atomicMax(&colMaxEnc[col0 + t], cmax[t]);
}

// sparsemax support is confined to z > max-1 (tau >= max-1 since p_max <= 1)
__global__ void k_collect(const float* __restrict__ Z, const unsigned* __restrict__ colMaxEnc,
                          int* __restrict__ candCount, int* __restrict__ candIdx,
                          float* __restrict__ candVal, const int* __restrict__ conv) {
  if (*conv) return;
  int col = threadIdx.x;
  int r0 = blockIdx.x * 128;
  float thr = decf(colMaxEnc[col]) - 1.0f;
  for (int r = 0; r < 128; ++r) {
    float z = Z[(size_t)(r0 + r) * BATCH + col];
    if (z > thr) {
      int p = atomicAdd(&candCount[col], 1);
      if (p < CAP) {
        candIdx[col * CAP + p] = r0 + r;
        candVal[col * CAP + p] = z;
      }
    }
  }
}

// tau (exact sparsemax over tiny candidate set) + fixed-point check, one block.
__global__ void k_tau_check(const int* __restrict__ candCount, int* __restrict__ candIdx,
                            float* __restrict__ candVal, int* __restrict__ suppK,
                            float* __restrict__ tauArr,
                            int* __restrict__ prevK, int* __restrict__ prevIdx,
                            float* __restrict__ prevP, int* __restrict__ conv) {
  if (*conv) return;
  __shared__ int all_same;
  int b = threadIdx.x;
  if (b == 0) all_same = 1;
  int m = candCount[b];
  if (m > CAP) m = CAP;
  float cv[CAP]; int ci[CAP];
  for (int j = 0; j < m; ++j) { cv[j] = candVal[b * CAP + j]; ci[j] = candIdx[b * CAP + j]; }
  for (int j = 1; j < m; ++j) {          // insertion sort descending (makes
    float v = cv[j]; int id = ci[j];     // order deterministic despite atomics)
    int s = j - 1;
    while (s >= 0 && cv[s] < v) { cv[s + 1] = cv[s]; ci[s + 1] = ci[s]; --s; }
    cv[s + 1] = v; ci[s + 1] = id;
  }
  float cum = 0.f; int k = 0; float tau = 0.f;
  for (int j = 0; j < m; ++j) {
    cum += cv[j];
    float tj = (cum - 1.0f) / (float)(j + 1);
    if (cv[j] > tj) { k = j + 1; tau = tj; }
  }
  suppK[b] = k;
  tauArr[b] = tau;
  for (int j = 0; j < m; ++j) { candVal[b * CAP + j] = cv[j]; candIdx[b * CAP + j] = ci[j]; }
  __syncthreads();
  // fixed-point: p_t == p_{t-1} bitwise for all columns -> later iters identical
  int same = (k == prevK[b]);
  for (int j = 0; j < k && same; ++j) {
    float p = cv[j] - tau;
    same = (ci[j] == prevIdx[b * CAP + j]) && (p == prevP[b * CAP + j]);
  }
  if (!same) all_same = 0;
  prevK[b] = k;
  for (int j = 0; j < k; ++j) {
    prevIdx[b * CAP + j] = ci[j];
    prevP[b * CAP + j]   = cv[j] - tau;
  }
  __syncthreads();
  if (b == 0 && all_same) *conv = 1;
}

// QT[b][:] = sum_j (cv_j - tau) * X[idx_j][:]  (exact fp32 from original X)
__global__ void k_qupdate(const float* __restrict__ X, const int* __restrict__ candIdx,
                          const float* __restrict__ candVal, const int* __restrict__ suppK,
                          const float* __restrict__ tauArr, float* __restrict__ QT,
                          const int* __restrict__ conv) {
  if (*conv) return;
  int b = blockIdx.x;
  int t = threadIdx.x;
  int k = suppK[b];
  float tau = tauArr[b];
  float a0 = 0.f, a1 = 0.f, a2 = 0.f, a3 = 0.f;
  for (int j = 0; j < k; ++j) {
    float wgt = candVal[b * CAP + j] - tau;
    const float* xr = X + (size_t)candIdx[b * CAP + j] * DF;
    a0 += wgt * xr[t];
    a1 += wgt * xr[t + 256];
    a2 += wgt * xr[t + 512];
    a3 += wgt * xr[t + 768];
  }
  QT[(size_t)b * DF + t]       = a0;
  QT[(size_t)b * DF + t + 256] = a1;
  QT[(size_t)b * DF + t + 512] = a2;
  QT[(size_t)b * DF + t + 768] = a3;
}

// d_out pre-zeroed; write only the support entries of p
__global__ void k_scatter(const int* __restrict__ candIdx, const float* __restrict__ candVal,
                          const int* __restrict__ suppK, const float* __restrict__ tauArr,
                          float* __restrict__ out) {
  int b = blockIdx.x * blockDim.x + threadIdx.x;
  if (b >= BATCH) return;
  int k = suppK[b];
  float tau = tauArr[b];
  for (int j = 0; j < k; ++j)
    out[(size_t)candIdx[b * CAP + j] * BATCH + b] = candVal[b * CAP + j] - tau;
}

extern "C" void kernel_launch(void* const* d_in, const int* in_sizes, int n_in,
                              void* d_out, int out_size, void* d_ws, size_t ws_size,
                              hipStream_t stream) {
  const float* X = (const float*)d_in[0];   // [16384][1024]
  const float* Q = (const float*)d_in[1];   // [1024][512]
  float* out = (float*)d_out;               // [16384][512]

  char* ws = (char*)d_ws;
  float*    Z   = (float*)ws;                               ws += (size_t)NPAT * BATCH * 4;  // 32 MB
  ushortT*  Xh  = (ushortT*)ws;                             ws += (size_t)NPAT * DF * 2;     // 32 MB
  ushortT*  Xl  = (ushortT*)ws;                             ws += (size_t)NPAT * DF * 2;     // 32 MB
  float*    QT  = (float*)ws;                               ws += (size_t)BATCH * DF * 4;    //  2 MB
  ushortT*  Qh  = (ushortT*)ws;                             ws += (size_t)BATCH * DF * 2;    //  1 MB
  ushortT*  Ql  = (ushortT*)ws;                             ws += (size_t)BATCH * DF * 2;    //  1 MB
  unsigned* colMaxEnc = (unsigned*)ws;                      ws += BATCH * 4;
  int*      candCount = (int*)ws;                           ws += BATCH * 4;
  int*      candIdx   = (int*)ws;                           ws += BATCH * CAP * 4;
  float*    candVal   = (float*)ws;                         ws += BATCH * CAP * 4;
  int*      suppK     = (int*)ws;                           ws += BATCH * 4;
  float*    tauArr    = (float*)ws;                         ws += BATCH * 4;
  int*      prevK     = (int*)ws;                           ws += BATCH * 4;
  int*      prevIdx   = (int*)ws;                           ws += BATCH * CAP * 4;
  float*    prevP     = (float*)ws;                         ws += BATCH * CAP * 4;
  int*      conv      = (int*)ws;
  // prevK/prevIdx start 0xAA-poisoned -> iter-1 check can't spuriously match.

  hipMemsetAsync(d_out, 0, (size_t)out_size * sizeof(float), stream);
  hipMemsetAsync(conv, 0, sizeof(int), stream);

  k_transpose<<<dim3(BATCH / 32, DF / 32), 256, 0, stream>>>(Q, QT);
  k_xsplit<<<NPAT * DF / 4 / 256, 256, 0, stream>>>((const float4*)X, (unsigned*)Xh, (unsigned*)Xl);

  for (int it = 0; it < MAXIT; ++it) {
    k_qsplit<<<BATCH * DF / 4 / 256, 256, 0, stream>>>((const float4*)QT, (unsigned*)Qh,
                                                       (unsigned*)Ql, colMaxEnc, candCount, conv);
    k_gemm<<<dim3(BATCH / 128, NPAT / 128), 256, 0, stream>>>(Xh, Xl, Qh, Ql, Z, colMaxEnc, conv);
    k_collect<<<NPAT / 128, BATCH, 0, stream>>>(Z, colMaxEnc, candCount, candIdx, candVal, conv);
    k_tau_check<<<1, BATCH, 0, stream>>>(candCount, candIdx, candVal, suppK, tauArr,
                                         prevK, prevIdx, prevP, conv);
    if (it < MAXIT - 1)
      k_qupdate<<<BATCH, 256, 0, stream>>>(X, candIdx, candVal, suppK, tauArr, QT, conv);
  }
  k_scatter<<<2, 256, 0, stream>>>(candIdx, candVal, suppK, tauArr, out);
}

// Round 8
// 681.804 us; speedup vs baseline: 3.6356x; 1.4771x over previous
//
#include <hip/hip_runtime.h>
#include <hip/hip_bf16.h>

#define NPAT  16384
#define DF    1024
#define BATCH 512
#define CAP   256   // raw candidate push buffer per column
#define SUP   16    // max support kept after exact filter
#define MAXIT 8

typedef __attribute__((ext_vector_type(8))) short short8v;  // 8 bf16
typedef __attribute__((ext_vector_type(4))) float f32x4;
typedef unsigned short ushortT;

__device__ __forceinline__ unsigned encf(float f) {
  unsigned u = __float_as_uint(f);
  return (u & 0x80000000u) ? ~u : (u | 0x80000000u);
}
__device__ __forceinline__ float decf(unsigned e) {
  unsigned u = (e & 0x80000000u) ? (e & 0x7FFFFFFFu) : ~e;
  return __uint_as_float(u);
}

// QT[n][k] = Q[k][n]
__global__ void k_transpose(const float* __restrict__ Q, float* __restrict__ QT) {
  __shared__ float tile[32][33];
  int tx = threadIdx.x & 31;
  int ty = threadIdx.x >> 5;
  int n0 = blockIdx.x * 32;
  int k0 = blockIdx.y * 32;
#pragma unroll
  for (int s = 0; s < 4; ++s)
    tile[ty + 8 * s][tx] = Q[(size_t)(k0 + ty + 8 * s) * BATCH + n0 + tx];
  __syncthreads();
#pragma unroll
  for (int s = 0; s < 4; ++s)
    QT[(size_t)(n0 + ty + 8 * s) * DF + k0 + tx] = tile[tx][ty + 8 * s];
}

// fp32 -> (hi bf16, lo bf16 residual): x = hi + lo + O(2^-17 |x|)
__device__ __forceinline__ void bsplit(float x, ushortT& h, ushortT& l) {
  __hip_bfloat16 hb = __float2bfloat16(x);
  float hf = __bfloat162float(hb);
  __hip_bfloat16 lb = __float2bfloat16(x - hf);
  h = *(ushortT*)&hb;
  l = *(ushortT*)&lb;
}

__global__ void k_xsplit(const float4* __restrict__ X4, unsigned* __restrict__ Xh,
                         unsigned* __restrict__ Xl) {
  size_t i = (size_t)blockIdx.x * blockDim.x + threadIdx.x;  // 4 elems/thread
  float4 v = X4[i];
  ushortT h0, h1, h2, h3, l0, l1, l2, l3;
  bsplit(v.x, h0, l0); bsplit(v.y, h1, l1);
  bsplit(v.z, h2, l2); bsplit(v.w, h3, l3);
  Xh[2 * i]     = (unsigned)h0 | ((unsigned)h1 << 16);
  Xh[2 * i + 1] = (unsigned)h2 | ((unsigned)h3 << 16);
  Xl[2 * i]     = (unsigned)l0 | ((unsigned)l1 << 16);
  Xl[2 * i + 1] = (unsigned)l2 | ((unsigned)l3 << 16);
}

// Initial Q split from QT; blocks 0,1 also clear the per-iter counters.
__global__ void k_qsplit0(const float4* __restrict__ QT4, unsigned* __restrict__ Qh,
                          unsigned* __restrict__ Ql, unsigned* __restrict__ colMaxEnc,
                          int* __restrict__ candCount) {
  int t = threadIdx.x;
  if (blockIdx.x < 2) {
    colMaxEnc[blockIdx.x * 256 + t] = 0u;
    candCount[blockIdx.x * 256 + t] = 0;
  }
  size_t i = (size_t)blockIdx.x * blockDim.x + t;
  float4 v = QT4[i];
  ushortT h0, h1, h2, h3, l0, l1, l2, l3;
  bsplit(v.x, h0, l0); bsplit(v.y, h1, l1);
  bsplit(v.z, h2, l2); bsplit(v.w, h3, l3);
  Qh[2 * i]     = (unsigned)h0 | ((unsigned)h1 << 16);
  Qh[2 * i + 1] = (unsigned)h2 | ((unsigned)h3 << 16);
  Ql[2 * i]     = (unsigned)l0 | ((unsigned)l1 << 16);
  Ql[2 * i + 1] = (unsigned)l2 | ((unsigned)l3 << 16);
}

// bf16x3 emulated-fp32 GEMM, NO Z materialization.
// Per 64-k chunk: stage Xh/Xl/Qh/Ql tiles (64 KB LDS), 3 passes (h*h, h*l, l*h),
// 96 MFMAs per barrier pair. Epilogue: col-max atomics + conservative-threshold
// candidate push (superset of sparsemax support; exact filter in k_tau_check).
__global__ __launch_bounds__(256, 2) void k_gemm(
    const ushortT* __restrict__ Xh, const ushortT* __restrict__ Xl,
    const ushortT* __restrict__ Qh, const ushortT* __restrict__ Ql,
    unsigned* __restrict__ colMaxEnc, int* __restrict__ candCount,
    int* __restrict__ candIdx, float* __restrict__ candVal,
    const int* __restrict__ conv) {
  if (*conv) return;
  __shared__ ushortT Ah[128 * 64], Al[128 * 64], Bh[128 * 64], Bl[128 * 64];
  __shared__ unsigned cmax[128];
  __shared__ float cthr[128];
  const int t  = threadIdx.x;
  const int l  = t & 63;
  const int w  = t >> 6;
  const int wr = w >> 1, wc = w & 1;
  const int lr = l & 15;
  const int lk = l >> 4;
  // XCD chunk swizzle: co-locate the 4 x-siblings of each A-panel on one XCD.
  const int lin = blockIdx.y * 4 + blockIdx.x;          // 512 blocks
  const int nid = (lin & 7) * 64 + (lin >> 3);          // bijective (512%8==0)
  const int bx = nid & 3, by = nid >> 2;
  const int row0 = by * 128, col0 = bx * 128;

  f32x4 acc[4][4];
#pragma unroll
  for (int i = 0; i < 4; ++i)
#pragma unroll
    for (int j = 0; j < 4; ++j) acc[i][j] = (f32x4)0.f;

  int rA[4], sA[4];
#pragma unroll
  for (int i = 0; i < 4; ++i) {
    int id = i * 256 + t;
    int r = id >> 3, c = id & 7;
    rA[i] = r;
    sA[i] = ((c ^ (r & 7)) << 3);   // pre-swizzled global k-offset (shorts)
  }

  uint4 pah[4], pal[4], pbh[4], pbl[4];
#pragma unroll
  for (int i = 0; i < 4; ++i) {     // prefetch chunk 0
    size_t ao = (size_t)(row0 + rA[i]) * DF + sA[i];
    size_t bo = (size_t)(col0 + rA[i]) * DF + sA[i];
    pah[i] = *(const uint4*)(Xh + ao);
    pal[i] = *(const uint4*)(Xl + ao);
    pbh[i] = *(const uint4*)(Qh + bo);
    pbl[i] = *(const uint4*)(Ql + bo);
  }

  for (int kc = 0; kc < 16; ++kc) {
    __syncthreads();
#pragma unroll
    for (int i = 0; i < 4; ++i) {   // linear LDS writes (conflict-free)
      int id = i * 256 + t;
      *(uint4*)(&Ah[id * 8]) = pah[i];
      *(uint4*)(&Al[id * 8]) = pal[i];
      *(uint4*)(&Bh[id * 8]) = pbh[i];
      *(uint4*)(&Bl[id * 8]) = pbl[i];
    }
    __syncthreads();
    if (kc < 15) {
      int kb = (kc + 1) * 64;
#pragma unroll
      for (int i = 0; i < 4; ++i) {
        size_t ao = (size_t)(row0 + rA[i]) * DF + kb + sA[i];
        size_t bo = (size_t)(col0 + rA[i]) * DF + kb + sA[i];
        pah[i] = *(const uint4*)(Xh + ao);
        pal[i] = *(const uint4*)(Xl + ao);
        pbh[i] = *(const uint4*)(Qh + bo);
        pbl[i] = *(const uint4*)(Ql + bo);
      }
    }
#pragma unroll
    for (int pass = 0; pass < 3; ++pass) {
      const ushortT* As = (pass == 2) ? Al : Ah;
      const ushortT* Bs = (pass == 1) ? Bl : Bh;
#pragma unroll
      for (int kk = 0; kk < 2; ++kk) {
        short8v af[4], bf[4];
#pragma unroll
        for (int i = 0; i < 4; ++i) {
          int row = wr * 64 + i * 16 + lr;
          int ch = (kk * 4 + lk) ^ (row & 7);
          af[i] = *(const short8v*)(&As[row * 64 + ch * 8]);
        }
#pragma unroll
        for (int j = 0; j < 4; ++j) {
          int col = wc * 64 + j * 16 + lr;
          int ch = (kk * 4 + lk) ^ (col & 7);
          bf[j] = *(const short8v*)(&Bs[col * 64 + ch * 8]);
        }
#pragma unroll
        for (int i = 0; i < 4; ++i)
#pragma unroll
          for (int j = 0; j < 4; ++j)
            acc[i][j] = __builtin_amdgcn_mfma_f32_16x16x32_bf16(af[i], bf[j], acc[i][j], 0, 0, 0);
      }
    }
  }

  // --- epilogue: column max + conservative candidate push (no Z store) ---
  __syncthreads();
  if (t < 128) cmax[t] = 0u;
  __syncthreads();
#pragma unroll
  for (int j = 0; j < 4; ++j) {
    float cm = -3.4e38f;
#pragma unroll
    for (int i = 0; i < 4; ++i)
#pragma unroll
      for (int q = 0; q < 4; ++q) cm = fmaxf(cm, acc[i][j][q]);
    cm = fmaxf(cm, __shfl_xor(cm, 16));   // reduce across lk groups
    cm = fmaxf(cm, __shfl_xor(cm, 32));
    if (lk == 0) atomicMax(&cmax[wc * 64 + j * 16 + lr], encf(cm));
  }
  __syncthreads();
  if (t < 128) {
    unsigned old = atomicMax(&colMaxEnc[col0 + t], cmax[t]);
    unsigned snap = old > cmax[t] ? old : cmax[t];   // monotone encoding
    cthr[t] = decf(snap) - 1.0f;         // <= final_max - 1 -> superset push
  }
  __syncthreads();
#pragma unroll
  for (int j = 0; j < 4; ++j) {
    int cl = wc * 64 + j * 16 + lr;
    float thr = cthr[cl];
    int gcol = col0 + cl;
#pragma unroll
    for (int i = 0; i < 4; ++i) {
      int rbase = row0 + wr * 64 + i * 16 + lk * 4;
#pragma unroll
      for (int q = 0; q < 4; ++q) {
        float v = acc[i][j][q];
        if (v > thr) {
          int p = atomicAdd(&candCount[gcol], 1);
          if (p < CAP) {
            candIdx[gcol * CAP + p] = rbase + q;
            candVal[gcol * CAP + p] = v;
          }
        }
      }
    }
  }
}

// Exact sparsemax on the filtered candidate set + fixed-point check + counter
// clear for the next iteration. One block, 512 threads (thread = column).
__global__ void k_tau_check(int* __restrict__ candCount, const int* __restrict__ candIdx,
                            const float* __restrict__ candVal, unsigned* __restrict__ colMaxEnc,
                            int* __restrict__ suppK, int* __restrict__ suppIdx,
                            float* __restrict__ suppP,
                            int* __restrict__ prevK, int* __restrict__ prevIdx,
                            float* __restrict__ prevP, int* __restrict__ conv) {
  if (*conv) return;
  __shared__ int all_same;
  int b = threadIdx.x;
  if (b == 0) all_same = 1;
  int m = candCount[b];
  if (m > CAP) m = CAP;
  float gmax = decf(colMaxEnc[b]);
  float thr = gmax - 1.0f;
  float cv[SUP]; int ci[SUP];
  int n = 0;
  for (int j = 0; j < m; ++j) {          // exact filter: true support is here
    float v = candVal[b * CAP + j];
    if (v > thr && n < SUP) { cv[n] = v; ci[n] = candIdx[b * CAP + j]; ++n; }
  }
  for (int j = 1; j < n; ++j) {          // sort desc (idx tie-break: determinism)
    float v = cv[j]; int id = ci[j];
    int s = j - 1;
    while (s >= 0 && (cv[s] < v || (cv[s] == v && ci[s] > id))) {
      cv[s + 1] = cv[s]; ci[s + 1] = ci[s]; --s;
    }
    cv[s + 1] = v; ci[s + 1] = id;
  }
  float cum = 0.f; int k = 0; float tau = 0.f;
  for (int j = 0; j < n; ++j) {
    cum += cv[j];
    float tj = (cum - 1.0f) / (float)(j + 1);
    if (cv[j] > tj) { k = j + 1; tau = tj; }
  }
  suppK[b] = k;
  int same = (k == prevK[b]);
  for (int j = 0; j < k; ++j) {
    float p = cv[j] - tau;
    same = same && (ci[j] == prevIdx[b * SUP + j]) && (p == prevP[b * SUP + j]);
    suppIdx[b * SUP + j] = ci[j];
    suppP[b * SUP + j]   = p;
    prevIdx[b * SUP + j] = ci[j];
    prevP[b * SUP + j]   = p;
  }
  prevK[b] = k;
  if (!same) all_same = 0;
  colMaxEnc[b] = 0u;                     // reset for next iteration's gemm
  candCount[b] = 0;
  __syncthreads();
  if (b == 0 && all_same) *conv = 1;     // p is a fixed point -> skip the rest
}

// Q_{t+1}(:,b) = sum_j p_j X[idx_j,:], written directly as bf16 hi/lo splits.
__global__ void k_qupd_split(const float* __restrict__ X, const int* __restrict__ suppK,
                             const int* __restrict__ suppIdx, const float* __restrict__ suppP,
                             unsigned* __restrict__ Qh, unsigned* __restrict__ Ql,
                             const int* __restrict__ conv) {
  if (*conv) return;
  int b = blockIdx.x;
  int t = threadIdx.x;
  int k = suppK[b];
  float a0 = 0.f, a1 = 0.f, a2 = 0.f, a3 = 0.f;
  for (int j = 0; j < k; ++j) {
    float wgt = suppP[b * SUP + j];
    const float* xr = X + (size_t)suppIdx[b * SUP + j] * DF;
    a0 += wgt * xr[2 * t];
    a1 += wgt * xr[2 * t + 1];
    a2 += wgt * xr[512 + 2 * t];
    a3 += wgt * xr[512 + 2 * t + 1];
  }
  ushortT h0, h1, h2, h3, l0, l1, l2, l3;
  bsplit(a0, h0, l0); bsplit(a1, h1, l1);
  bsplit(a2, h2, l2); bsplit(a3, h3, l3);
  Qh[b * 512 + t]       = (unsigned)h0 | ((unsigned)h1 << 16);
  Ql[b * 512 + t]       = (unsigned)l0 | ((unsigned)l1 << 16);
  Qh[b * 512 + 256 + t] = (unsigned)h2 | ((unsigned)h3 << 16);
  Ql[b * 512 + 256 + t] = (unsigned)l2 | ((unsigned)l3 << 16);
}

// d_out pre-zeroed; write only the support entries of p
__global__ void k_scatter(const int* __restrict__ suppK, const int* __restrict__ suppIdx,
                          const float* __restrict__ suppP, float* __restrict__ out) {
  int b = blockIdx.x * blockDim.x + threadIdx.x;
  if (b >= BATCH) return;
  int k = suppK[b];
  for (int j = 0; j < k; ++j)
    out[(size_t)suppIdx[b * SUP + j] * BATCH + b] = suppP[b * SUP + j];
}

extern "C" void kernel_launch(void* const* d_in, const int* in_sizes, int n_in,
                              void* d_out, int out_size, void* d_ws, size_t ws_size,
                              hipStream_t stream) {
  const float* X = (const float*)d_in[0];   // [16384][1024]
  const float* Q = (const float*)d_in[1];   // [1024][512]
  float* out = (float*)d_out;               // [16384][512]

  char* ws = (char*)d_ws;
  ushortT*  Xh  = (ushortT*)ws;             ws += (size_t)NPAT * DF * 2;    // 32 MB
  ushortT*  Xl  = (ushortT*)ws;             ws += (size_t)NPAT * DF * 2;    // 32 MB
  float*    QT  = (float*)ws;               ws += (size_t)BATCH * DF * 4;   //  2 MB
  ushortT*  Qh  = (ushortT*)ws;             ws += (size_t)BATCH * DF * 2;   //  1 MB
  ushortT*  Ql  = (ushortT*)ws;             ws += (size_t)BATCH * DF * 2;   //  1 MB
  unsigned* colMaxEnc = (unsigned*)ws;      ws += BATCH * 4;
  int*      candCount = (int*)ws;           ws += BATCH * 4;
  int*      candIdx   = (int*)ws;           ws += BATCH * CAP * 4;          // 512 KB
  float*    candVal   = (float*)ws;         ws += BATCH * CAP * 4;          // 512 KB
  int*      suppK     = (int*)ws;           ws += BATCH * 4;
  int*      suppIdx   = (int*)ws;           ws += BATCH * SUP * 4;
  float*    suppP     = (float*)ws;         ws += BATCH * SUP * 4;
  int*      prevK     = (int*)ws;           ws += BATCH * 4;
  int*      prevIdx   = (int*)ws;           ws += BATCH * SUP * 4;
  float*    prevP     = (float*)ws;         ws += BATCH * SUP * 4;
  int*      conv      = (int*)ws;
  // prevK starts 0xAA-poisoned -> iteration-1 check cannot spuriously match.

  (void)hipMemsetAsync(d_out, 0, (size_t)out_size * sizeof(float), stream);
  (void)hipMemsetAsync(conv, 0, sizeof(int), stream);

  k_transpose<<<dim3(BATCH / 32, DF / 32), 256, 0, stream>>>(Q, QT);
  k_xsplit<<<NPAT * DF / 4 / 256, 256, 0, stream>>>((const float4*)X, (unsigned*)Xh, (unsigned*)Xl);
  k_qsplit0<<<BATCH * DF / 4 / 256, 256, 0, stream>>>((const float4*)QT, (unsigned*)Qh,
                                                      (unsigned*)Ql, colMaxEnc, candCount);

  for (int it = 0; it < MAXIT; ++it) {
    k_gemm<<<dim3(4, 128), 256, 0, stream>>>(Xh, Xl, Qh, Ql, colMaxEnc, candCount,
                                             candIdx, candVal, conv);
    k_tau_check<<<1, BATCH, 0, stream>>>(candCount, candIdx, candVal, colMaxEnc,
                                         suppK, suppIdx, suppP,
                                         prevK, prevIdx, prevP, conv);
    if (it < MAXIT - 1)
      k_qupd_split<<<BATCH, 256, 0, stream>>>(X, suppK, suppIdx, suppP,
                                              (unsigned*)Qh, (unsigned*)Ql, conv);
  }
  k_scatter<<<2, 256, 0, stream>>>(suppK, suppIdx, suppP, out);
}

// Round 9
// 348.918 us; speedup vs baseline: 7.1041x; 1.9541x over previous
//
#include <hip/hip_runtime.h>
#include <hip/hip_bf16.h>

#define NPAT  16384
#define DF    1024
#define BATCH 512
#define CAP   256   // raw candidate slots per column (== k_post thread count)
#define SUP   16    // max support kept after exact filter
#define MAXIT 8

typedef __attribute__((ext_vector_type(8))) short short8v;  // 8 bf16
typedef __attribute__((ext_vector_type(4))) float f32x4;
typedef unsigned short ushortT;

// async global->LDS, 16B per lane; LDS dest = wave-uniform base + lane*16
#define GLD16(gp, lp) __builtin_amdgcn_global_load_lds( \
    (const __attribute__((address_space(1))) void*)(gp), \
    (__attribute__((address_space(3))) void*)(lp), 16, 0, 0)

__device__ __forceinline__ unsigned encf(float f) {
  unsigned u = __float_as_uint(f);
  return (u & 0x80000000u) ? ~u : (u | 0x80000000u);
}
__device__ __forceinline__ float decf(unsigned e) {
  unsigned u = (e & 0x80000000u) ? (e & 0x7FFFFFFFu) : ~e;
  return __uint_as_float(u);
}

// QT[n][k] = Q[k][n]
__global__ void k_transpose(const float* __restrict__ Q, float* __restrict__ QT) {
  __shared__ float tile[32][33];
  int tx = threadIdx.x & 31;
  int ty = threadIdx.x >> 5;
  int n0 = blockIdx.x * 32;
  int k0 = blockIdx.y * 32;
#pragma unroll
  for (int s = 0; s < 4; ++s)
    tile[ty + 8 * s][tx] = Q[(size_t)(k0 + ty + 8 * s) * BATCH + n0 + tx];
  __syncthreads();
#pragma unroll
  for (int s = 0; s < 4; ++s)
    QT[(size_t)(n0 + ty + 8 * s) * DF + k0 + tx] = tile[tx][ty + 8 * s];
}

// fp32 -> (hi bf16, lo bf16 residual): x = hi + lo + O(2^-17 |x|)
__device__ __forceinline__ void bsplit(float x, ushortT& h, ushortT& l) {
  __hip_bfloat16 hb = __float2bfloat16(x);
  float hf = __bfloat162float(hb);
  __hip_bfloat16 lb = __float2bfloat16(x - hf);
  h = *(ushortT*)&hb;
  l = *(ushortT*)&lb;
}

__global__ void k_xsplit(const float4* __restrict__ X4, unsigned* __restrict__ Xh,
                         unsigned* __restrict__ Xl) {
  size_t i = (size_t)blockIdx.x * blockDim.x + threadIdx.x;  // 4 elems/thread
  float4 v = X4[i];
  ushortT h0, h1, h2, h3, l0, l1, l2, l3;
  bsplit(v.x, h0, l0); bsplit(v.y, h1, l1);
  bsplit(v.z, h2, l2); bsplit(v.w, h3, l3);
  Xh[2 * i]     = (unsigned)h0 | ((unsigned)h1 << 16);
  Xh[2 * i + 1] = (unsigned)h2 | ((unsigned)h3 << 16);
  Xl[2 * i]     = (unsigned)l0 | ((unsigned)l1 << 16);
  Xl[2 * i + 1] = (unsigned)l2 | ((unsigned)l3 << 16);
}

// Initial Q split from QT; blocks 0,1 also clear the per-iter counters.
__global__ void k_qsplit0(const float4* __restrict__ QT4, unsigned* __restrict__ Qh,
                          unsigned* __restrict__ Ql, unsigned* __restrict__ colMaxEnc,
                          int* __restrict__ candCount) {
  int t = threadIdx.x;
  if (blockIdx.x < 2) {
    colMaxEnc[blockIdx.x * 256 + t] = 0u;
    candCount[blockIdx.x * 256 + t] = 0;
  }
  size_t i = (size_t)blockIdx.x * blockDim.x + t;
  float4 v = QT4[i];
  ushortT h0, h1, h2, h3, l0, l1, l2, l3;
  bsplit(v.x, h0, l0); bsplit(v.y, h1, l1);
  bsplit(v.z, h2, l2); bsplit(v.w, h3, l3);
  Qh[2 * i]     = (unsigned)h0 | ((unsigned)h1 << 16);
  Qh[2 * i + 1] = (unsigned)h2 | ((unsigned)h3 << 16);
  Ql[2 * i]     = (unsigned)l0 | ((unsigned)l1 << 16);
  Ql[2 * i + 1] = (unsigned)l2 | ((unsigned)l3 << 16);
}

// bf16x3 emulated-fp32 GEMM, no Z store, no register prefetch (async
// global_load_lds staging -> no spill). Per 64-k chunk: stage Xh/Xl/Qh/Ql
// tiles (64 KB LDS), 3 passes (h*h, h*l, l*h), 96 MFMAs per barrier pair.
// Epilogue: col-max atomics + conservative-threshold candidate push.
__global__ __launch_bounds__(256, 2) void k_gemm(
    const ushortT* __restrict__ Xh, const ushortT* __restrict__ Xl,
    const ushortT* __restrict__ Qh, const ushortT* __restrict__ Ql,
    unsigned* __restrict__ colMaxEnc, int* __restrict__ candCount,
    int* __restrict__ candIdx, float* __restrict__ candVal,
    const int* __restrict__ conv) {
  if (*conv) return;
  __shared__ ushortT Ah[128 * 64], Al[128 * 64], Bh[128 * 64], Bl[128 * 64];
  __shared__ unsigned cmax[128];
  __shared__ float cthr[128];
  const int t  = threadIdx.x;
  const int l  = t & 63;
  const int w  = t >> 6;
  const int wr = w >> 1, wc = w & 1;
  const int lr = l & 15;
  const int lk = l >> 4;
  // XCD chunk swizzle: co-locate the 4 x-siblings of each A-panel on one XCD.
  const int lin = blockIdx.y * 4 + blockIdx.x;          // 512 blocks
  const int nid = (lin & 7) * 64 + (lin >> 3);          // bijective (512%8==0)
  const int bx = nid & 3, by = nid >> 2;
  const int row0 = by * 128, col0 = bx * 128;

  f32x4 acc[4][4];
#pragma unroll
  for (int i = 0; i < 4; ++i)
#pragma unroll
    for (int j = 0; j < 4; ++j) acc[i][j] = (f32x4)0.f;

  // staging geometry: id = i*256+t covers [row 0..127][16B-chunk 0..7];
  // global k-offset pre-swizzled (c ^ (r&7)), LDS dest linear ->
  // LDS[r][c] holds global chunk c^(r&7); read side inverts with same XOR.
  int rA[4], sA[4], dstB[4];
#pragma unroll
  for (int i = 0; i < 4; ++i) {
    int id = i * 256 + t;
    int r = id >> 3, c = id & 7;
    rA[i]   = r;
    sA[i]   = ((c ^ (r & 7)) << 3);        // source k-offset (shorts)
    dstB[i] = (i * 256 + (t & 192)) * 8;   // wave-uniform LDS base (shorts)
  }

  for (int kc = 0; kc < 16; ++kc) {
    int kb = kc * 64;
    __syncthreads();                        // prior compute done reading LDS
#pragma unroll
    for (int i = 0; i < 4; ++i) {           // async stage: 16 loads, no VGPRs
      size_t ao = (size_t)(row0 + rA[i]) * DF + kb + sA[i];
      size_t bo = (size_t)(col0 + rA[i]) * DF + kb + sA[i];
      GLD16(Xh + ao, &Ah[dstB[i]]);
      GLD16(Xl + ao, &Al[dstB[i]]);
      GLD16(Qh + bo, &Bh[dstB[i]]);
      GLD16(Ql + bo, &Bl[dstB[i]]);
    }
    __syncthreads();                        // compiler drains vmcnt(0) first
#pragma unroll
    for (int pass = 0; pass < 3; ++pass) {
      const ushortT* As = (pass == 2) ? Al : Ah;
      const ushortT* Bs = (pass == 1) ? Bl : Bh;
#pragma unroll
      for (int kk = 0; kk < 2; ++kk) {
        short8v af[4], bf[4];
#pragma unroll
        for (int i = 0; i < 4; ++i) {
          int row = wr * 64 + i * 16 + lr;
          int ch = (kk * 4 + lk) ^ (row & 7);
          af[i] = *(const short8v*)(&As[row * 64 + ch * 8]);
        }
#pragma unroll
        for (int j = 0; j < 4; ++j) {
          int col = wc * 64 + j * 16 + lr;
          int ch = (kk * 4 + lk) ^ (col & 7);
          bf[j] = *(const short8v*)(&Bs[col * 64 + ch * 8]);
        }
#pragma unroll
        for (int i = 0; i < 4; ++i)
#pragma unroll
          for (int j = 0; j < 4; ++j)
            acc[i][j] = __builtin_amdgcn_mfma_f32_16x16x32_bf16(af[i], bf[j], acc[i][j], 0, 0, 0);
      }
    }
  }

  // --- epilogue: column max + conservative candidate push (no Z store) ---
  __syncthreads();
  if (t < 128) cmax[t] = 0u;
  __syncthreads();
#pragma unroll
  for (int j = 0; j < 4; ++j) {
    float cm = -3.4e38f;
#pragma unroll
    for (int i = 0; i < 4; ++i)
#pragma unroll
      for (int q = 0; q < 4; ++q) cm = fmaxf(cm, acc[i][j][q]);
    cm = fmaxf(cm, __shfl_xor(cm, 16));   // reduce across lk groups
    cm = fmaxf(cm, __shfl_xor(cm, 32));
    if (lk == 0) atomicMax(&cmax[wc * 64 + j * 16 + lr], encf(cm));
  }
  __syncthreads();
  if (t < 128) {
    unsigned old = atomicMax(&colMaxEnc[col0 + t], cmax[t]);
    unsigned snap = old > cmax[t] ? old : cmax[t];   // monotone encoding
    cthr[t] = decf(snap) - 1.0f;         // <= final_max - 1 -> superset push
  }
  __syncthreads();
#pragma unroll
  for (int j = 0; j < 4; ++j) {
    int cl = wc * 64 + j * 16 + lr;
    float thr = cthr[cl];
    int gcol = col0 + cl;
#pragma unroll
    for (int i = 0; i < 4; ++i) {
      int rbase = row0 + wr * 64 + i * 16 + lk * 4;
#pragma unroll
      for (int q = 0; q < 4; ++q) {
        float v = acc[i][j][q];
        if (v > thr) {
          int p = atomicAdd(&candCount[gcol], 1);
          if (p < CAP) {
            candIdx[p * BATCH + gcol] = rbase + q;   // [CAP][BATCH] layout
            candVal[p * BATCH + gcol] = v;
          }
        }
      }
    }
  }
}

// Per-column postprocess: exact filter + sort + tau + fixed-point vote +
// fused Q-update. Block = column (512 blocks x 256 threads).
__global__ __launch_bounds__(256) void k_post(
    int* __restrict__ candCount, const int* __restrict__ candIdx,
    const float* __restrict__ candVal, unsigned* __restrict__ colMaxEnc,
    int* __restrict__ suppK, int* __restrict__ suppIdx, float* __restrict__ suppP,
    int* __restrict__ prevK, int* __restrict__ prevIdx, float* __restrict__ prevP,
    const float* __restrict__ X, unsigned* __restrict__ Qh, unsigned* __restrict__ Ql,
    int* __restrict__ conv, int* __restrict__ sameCount, int* __restrict__ doneCount,
    int doQupd) {
  if (*conv) return;
  const int b = blockIdx.x;
  const int t = threadIdx.x;
  __shared__ float scv[SUP];
  __shared__ int   sci[SUP];
  __shared__ float scw[SUP];
  __shared__ int scnt, sk;

  int m = candCount[b];
  if (m > CAP) m = CAP;
  float thr = decf(colMaxEnc[b]) - 1.0f;
  if (t == 0) scnt = 0;
  __syncthreads();
  if (t < m) {                           // coalesced filter: true support here
    float v = candVal[t * BATCH + b];
    if (v > thr) {
      int p = atomicAdd(&scnt, 1);
      if (p < SUP) { scv[p] = v; sci[p] = candIdx[t * BATCH + b]; }
    }
  }
  __syncthreads();

  if (t == 0) {
    int n = scnt < SUP ? scnt : SUP;
    float cv[SUP]; int ci[SUP];
    for (int j = 0; j < n; ++j) { cv[j] = scv[j]; ci[j] = sci[j]; }
    for (int j = 1; j < n; ++j) {        // sort desc, idx tie-break: determinism
      float v = cv[j]; int id = ci[j];
      int s = j - 1;
      while (s >= 0 && (cv[s] < v || (cv[s] == v && ci[s] > id))) {
        cv[s + 1] = cv[s]; ci[s + 1] = ci[s]; --s;
      }
      cv[s + 1] = v; ci[s + 1] = id;
    }
    float cum = 0.f; int k = 0; float tau = 0.f;
    for (int j = 0; j < n; ++j) {
      cum += cv[j];
      float tj = (cum - 1.0f) / (float)(j + 1);
      if (cv[j] > tj) { k = j + 1; tau = tj; }
    }
    suppK[b] = k;
    int same = (k == prevK[b]);
    for (int j = 0; j < k; ++j) {
      float p = cv[j] - tau;
      same = same && (ci[j] == prevIdx[b * SUP + j]) && (p == prevP[b * SUP + j]);
      suppIdx[b * SUP + j] = ci[j];
      suppP[b * SUP + j]   = p;
      prevIdx[b * SUP + j] = ci[j];
      prevP[b * SUP + j]   = p;
      scw[j] = p; sci[j] = ci[j];        // for the fused Q-update below
    }
    prevK[b] = k;
    sk = k;
    colMaxEnc[b] = 0u;                   // reset for next iteration's gemm
    candCount[b] = 0;
    // convergence vote: all 512 columns bitwise-identical -> conv=1
    if (same) atomicAdd(sameCount, 1);
    __threadfence();
    int d = atomicAdd(doneCount, 1);
    if (d == BATCH - 1) {                // last block finalizes + resets
      __threadfence();
      if (atomicAdd(sameCount, 0) == BATCH) atomicExch(conv, 1);
      atomicExch(sameCount, 0);
      atomicExch(doneCount, 0);
    }
  }
  __syncthreads();

  if (doQupd) {                          // Q_{t+1}(:,b) = sum_j p_j X[idx_j,:]
    int k = sk;
    float a0 = 0.f, a1 = 0.f, a2 = 0.f, a3 = 0.f;
    for (int j = 0; j < k; ++j) {
      float wgt = scw[j];
      const float* xr = X + (size_t)sci[j] * DF;
      a0 += wgt * xr[2 * t];
      a1 += wgt * xr[2 * t + 1];
      a2 += wgt * xr[512 + 2 * t];
      a3 += wgt * xr[512 + 2 * t + 1];
    }
    ushortT h0, h1, h2, h3, l0, l1, l2, l3;
    bsplit(a0, h0, l0); bsplit(a1, h1, l1);
    bsplit(a2, h2, l2); bsplit(a3, h3, l3);
    Qh[b * 512 + t]       = (unsigned)h0 | ((unsigned)h1 << 16);
    Ql[b * 512 + t]       = (unsigned)l0 | ((unsigned)l1 << 16);
    Qh[b * 512 + 256 + t] = (unsigned)h2 | ((unsigned)h3 << 16);
    Ql[b * 512 + 256 + t] = (unsigned)l2 | ((unsigned)l3 << 16);
  }
}

// d_out pre-zeroed; write only the support entries of p
__global__ void k_scatter(const int* __restrict__ suppK, const int* __restrict__ suppIdx,
                          const float* __restrict__ suppP, float* __restrict__ out) {
  int b = blockIdx.x * blockDim.x + threadIdx.x;
  if (b >= BATCH) return;
  int k = suppK[b];
  for (int j = 0; j < k; ++j)
    out[(size_t)suppIdx[b * SUP + j] * BATCH + b] = suppP[b * SUP + j];
}

extern "C" void kernel_launch(void* const* d_in, const int* in_sizes, int n_in,
                              void* d_out, int out_size, void* d_ws, size_t ws_size,
                              hipStream_t stream) {
  const float* X = (const float*)d_in[0];   // [16384][1024]
  const float* Q = (const float*)d_in[1];   // [1024][512]
  float* out = (float*)d_out;               // [16384][512]

  char* ws = (char*)d_ws;
  ushortT*  Xh  = (ushortT*)ws;             ws += (size_t)NPAT * DF * 2;    // 32 MB
  ushortT*  Xl  = (ushortT*)ws;             ws += (size_t)NPAT * DF * 2;    // 32 MB
  float*    QT  = (float*)ws;               ws += (size_t)BATCH * DF * 4;   //  2 MB
  ushortT*  Qh  = (ushortT*)ws;             ws += (size_t)BATCH * DF * 2;   //  1 MB
  ushortT*  Ql  = (ushortT*)ws;             ws += (size_t)BATCH * DF * 2;   //  1 MB
  unsigned* colMaxEnc = (unsigned*)ws;      ws += BATCH * 4;
  int*      candCount = (int*)ws;           ws += BATCH * 4;
  int*      candIdx   = (int*)ws;           ws += BATCH * CAP * 4;          // 512 KB
  float*    candVal   = (float*)ws;         ws += BATCH * CAP * 4;          // 512 KB
  int*      suppK     = (int*)ws;           ws += BATCH * 4;
  int*      suppIdx   = (int*)ws;           ws += BATCH * SUP * 4;
  float*    suppP     = (float*)ws;         ws += BATCH * SUP * 4;
  int*      prevK     = (int*)ws;           ws += BATCH * 4;
  int*      prevIdx   = (int*)ws;           ws += BATCH * SUP * 4;
  float*    prevP     = (float*)ws;         ws += BATCH * SUP * 4;
  int*      conv      = (int*)ws;           ws += 4;
  int*      sameCount = (int*)ws;           ws += 4;
  int*      doneCount = (int*)ws;
  // prevK starts 0xAA-poisoned -> iteration-1 check cannot spuriously match.

  (void)hipMemsetAsync(d_out, 0, (size_t)out_size * sizeof(float), stream);
  (void)hipMemsetAsync(conv, 0, 12, stream);   // conv, sameCount, doneCount

  k_transpose<<<dim3(BATCH / 32, DF / 32), 256, 0, stream>>>(Q, QT);
  k_xsplit<<<NPAT * DF / 4 / 256, 256, 0, stream>>>((const float4*)X, (unsigned*)Xh, (unsigned*)Xl);
  k_qsplit0<<<BATCH * DF / 4 / 256, 256, 0, stream>>>((const float4*)QT, (unsigned*)Qh,
                                                      (unsigned*)Ql, colMaxEnc, candCount);

  for (int it = 0; it < MAXIT; ++it) {
    k_gemm<<<dim3(4, 128), 256, 0, stream>>>(Xh, Xl, Qh, Ql, colMaxEnc, candCount,
                                             candIdx, candVal, conv);
    k_post<<<BATCH, 256, 0, stream>>>(candCount, candIdx, candVal, colMaxEnc,
                                      suppK, suppIdx, suppP,
                                      prevK, prevIdx, prevP,
                                      X, (unsigned*)Qh, (unsigned*)Ql,
                                      conv, sameCount, doneCount,
                                      it < MAXIT - 1 ? 1 : 0);
  }
  k_scatter<<<2, 256, 0, stream>>>(suppK, suppIdx, suppP, out);
}